// Round 5
// baseline (599.682 us; speedup 1.0000x reference)
//
#include <hip/hip_runtime.h>
#include <hip/hip_bf16.h>

// CAPERNN_ContRoles_HPN — round 5: n-fast gemm grid (A L2 reuse), split GRU gemms (no zero
// blocks), 2-row/128-thread glue_attn (occupancy), merged glue_tail (gru+qws+final),
// 3-launch prep chain.
// M = BN = 16384, H=256, NH=4, HD=64, NA=15, NE=16, RD=8, NMOVE=6.

#define MROWS 16384

typedef __attribute__((ext_vector_type(8))) short short8;
typedef __attribute__((ext_vector_type(4))) float float4v;

__device__ __forceinline__ unsigned short f2b(float f) {
    __hip_bfloat16 h = __float2bfloat16(f);
    return *reinterpret_cast<unsigned short*>(&h);
}
__device__ __forceinline__ float b2f(unsigned short u) {
    __hip_bfloat16 h;
    *reinterpret_cast<unsigned short*>(&h) = u;
    return __bfloat162float(h);
}
__device__ __forceinline__ void gll16(const unsigned short* g, unsigned short* l) {
    __builtin_amdgcn_global_load_lds((const __attribute__((address_space(1))) void*)g,
                                     (__attribute__((address_space(3))) void*)l, 16, 0, 0);
}

// ---------------- prep: hidden->XG[264:520], own->OWNb, zero zbuf ----------------
__global__ void cvt_misc(const float* __restrict__ hidden, const float* __restrict__ ownf,
                         unsigned short* __restrict__ XG, unsigned short* __restrict__ OWNb,
                         unsigned short* __restrict__ zbuf) {
    int idx = blockIdx.x * 256 + threadIdx.x;
    const int nh = MROWS * 64;
    const int no = MROWS * 8;
    if (idx < nh) {
        int row = idx >> 6, c4 = (idx & 63) * 4;
        float4 v = *(const float4*)(hidden + (size_t)row * 256 + c4);
        unsigned short* d = XG + (size_t)row * 520 + 264 + c4;
        d[0] = f2b(v.x); d[1] = f2b(v.y); d[2] = f2b(v.z); d[3] = f2b(v.w);
    } else if (idx < nh + no) {
        int j = idx - nh;
        int row = j >> 3, c4 = (j & 7) * 4;
        float4 v = *(const float4*)(ownf + (size_t)row * 32 + c4);
        unsigned short* d = OWNb + (size_t)row * 32 + c4;
        d[0] = f2b(v.x); d[1] = f2b(v.y); d[2] = f2b(v.z); d[3] = f2b(v.w);
    } else if (idx < nh + no + 16) {
        ((uint4*)zbuf)[idx - nh - no] = make_uint4(0u, 0u, 0u, 0u);
    }
}

// ---------------- tiled compose ----------------
// type 0: matmul->bf16, 1: matmul->fp32, 2: cvt copy->bf16, 3: zero bf16, 4: copy fp32
struct TOp {
    int type;
    const float* A; int sAi, sAk;
    const float* B; int sBj, sBk;
    void* O; int sOi;
    int I, J, K;
    int nb; int aB, bB, oB;
    const float* bias1; const float* bias2;
};
struct TOpSet { int n; int tiles[26]; TOp ops[26]; };

__global__ __launch_bounds__(256)
void compose_tiled(TOpSet S) {
    int t = blockIdx.x;
    int op = 0;
    while (op < S.n && t >= S.tiles[op]) { t -= S.tiles[op]; op++; }
    if (op >= S.n) return;
    TOp o = S.ops[op];
    int ti = (o.I + 31) >> 5, tj = (o.J + 31) >> 5;
    int per = ti * tj;
    int b = t / per;
    int rem = t - b * per;
    int i0 = (rem / tj) * 32, j0 = (rem % tj) * 32;
    int tid = threadIdx.x;
    if (o.type >= 2) {
        for (int e = tid; e < 1024; e += 256) {
            int r = e >> 5, c = e & 31;
            int i = i0 + r, j = j0 + c;
            if (i < o.I && j < o.J) {
                long oidx = (long)b * o.oB + (long)i * o.sOi + j;
                if (o.type == 3) { ((unsigned short*)o.O)[oidx] = 0; }
                else {
                    float v = o.A[(long)b * o.aB + (long)i * o.sAi + (long)j * o.sAk];
                    if (o.type == 2) ((unsigned short*)o.O)[oidx] = f2b(v);
                    else ((float*)o.O)[oidx] = v;
                }
            }
        }
        return;
    }
    __shared__ float As[32][33];
    __shared__ float Bs[32][33];
    int tx = tid & 15, ty = tid >> 4;
    float a00 = 0.f, a01 = 0.f, a10 = 0.f, a11 = 0.f;
    const float* Ab = o.A + (long)b * o.aB;
    const float* Bb = o.B + (long)b * o.bB;
    for (int k0 = 0; k0 < o.K; k0 += 32) {
        for (int e = tid; e < 1024; e += 256) {
            int r = e >> 5, c = e & 31;
            As[r][c] = (i0 + r < o.I && k0 + c < o.K)
                       ? Ab[(long)(i0 + r) * o.sAi + (long)(k0 + c) * o.sAk] : 0.f;
            Bs[r][c] = (k0 + r < o.K && j0 + c < o.J)
                       ? Bb[(long)(j0 + c) * o.sBj + (long)(k0 + r) * o.sBk] : 0.f;
        }
        __syncthreads();
#pragma unroll
        for (int k = 0; k < 32; k++) {
            float x0 = As[ty * 2][k], x1 = As[ty * 2 + 1][k];
            float y0 = Bs[k][tx * 2], y1 = Bs[k][tx * 2 + 1];
            a00 += x0 * y0; a01 += x0 * y1; a10 += x1 * y0; a11 += x1 * y1;
        }
        __syncthreads();
    }
    int i = i0 + ty * 2, j = j0 + tx * 2;
    float vals[2][2] = {{a00, a01}, {a10, a11}};
#pragma unroll
    for (int di = 0; di < 2; di++)
#pragma unroll
        for (int dj = 0; dj < 2; dj++) {
            int ii = i + di, jj = j + dj;
            if (ii < o.I && jj < o.J) {
                float v = vals[di][dj];
                if (o.bias1) v += o.bias1[ii];
                if (o.bias2) v += o.bias2[ii];
                long oidx = (long)b * o.oB + (long)ii * o.sOi + jj;
                if (o.type == 0) ((unsigned short*)o.O)[oidx] = f2b(v);
                else ((float*)o.O)[oidx] = v;
            }
        }
}

// ---------------- bf16 MFMA GEMM (n-fast grid): C[MxN] = A[MxK] @ W[NxK]^T ----------------
__global__ __launch_bounds__(256, 4)
void gemm_bf16(const unsigned short* __restrict__ A, int lda,
               const unsigned short* __restrict__ W,
               const float* __restrict__ bias,
               unsigned short* __restrict__ C, int ldc,
               int N, int K, int act,
               const unsigned short* __restrict__ zbuf) {
    __shared__ __align__(16) unsigned short As[128 * 32];
    __shared__ __align__(16) unsigned short Bs[128 * 32];
    int tid = threadIdx.x;
    int n0 = blockIdx.x * 128, m0 = blockIdx.y * 128;
    int wave = tid >> 6, lane = tid & 63;
    int wm = (wave & 1) * 64, wn = (wave >> 1) * 64;
    int l16 = lane & 15, quad = lane >> 4;

    float4v acc[4][4];
#pragma unroll
    for (int i = 0; i < 4; i++)
#pragma unroll
        for (int j = 0; j < 4; j++) acc[i][j] = (float4v){0.f, 0.f, 0.f, 0.f};

    int s0 = tid, s1 = tid + 256;
    int row0 = s0 >> 2, seg0 = (s0 & 3) * 8;
    int row1 = s1 >> 2, seg1 = (s1 & 3) * 8;
    const unsigned short* Arow0 = A + (size_t)(m0 + row0) * lda;
    const unsigned short* Arow1 = A + (size_t)(m0 + row1) * lda;
    const unsigned short* Wrow0 = W + (size_t)(n0 + row0) * K;
    const unsigned short* Wrow1 = W + (size_t)(n0 + row1) * K;
    unsigned short* ldsA0 = As + (size_t)(wave * 64) * 8;
    unsigned short* ldsA1 = As + (size_t)(wave * 64 + 256) * 8;
    unsigned short* ldsB0 = Bs + (size_t)(wave * 64) * 8;
    unsigned short* ldsB1 = Bs + (size_t)(wave * 64 + 256) * 8;

    for (int k0 = 0; k0 < K; k0 += 32) {
        int ka0 = k0 + seg0, ka1 = k0 + seg1;
        gll16((ka0 < K) ? Arow0 + ka0 : zbuf, ldsA0);
        gll16((ka1 < K) ? Arow1 + ka1 : zbuf, ldsA1);
        gll16((ka0 < K) ? Wrow0 + ka0 : zbuf, ldsB0);
        gll16((ka1 < K) ? Wrow1 + ka1 : zbuf, ldsB1);
        __syncthreads();
        short8 a[4], b[4];
#pragma unroll
        for (int i = 0; i < 4; i++) {
            a[i] = *(const short8*)(&As[(wm + i * 16 + l16) * 32 + quad * 8]);
            b[i] = *(const short8*)(&Bs[(wn + i * 16 + l16) * 32 + quad * 8]);
        }
#pragma unroll
        for (int i = 0; i < 4; i++)
#pragma unroll
            for (int j = 0; j < 4; j++)
                acc[i][j] = __builtin_amdgcn_mfma_f32_16x16x32_bf16(a[i], b[j], acc[i][j], 0, 0, 0);
        __syncthreads();
    }
#pragma unroll
    for (int i = 0; i < 4; i++) {
#pragma unroll
        for (int j = 0; j < 4; j++) {
#pragma unroll
            for (int rr = 0; rr < 4; rr++) {
                int rowm = m0 + wm + i * 16 + quad * 4 + rr;
                int coln = wn + j * 16 + l16;
                float v = acc[i][j][rr];
                if (bias) v += bias[n0 + coln];
                if (act == 1) v = 0.5f * v * (1.f + erff(v * 0.70710678f));
                C[(size_t)rowm * ldc + n0 + coln] = f2b(v);
            }
        }
    }
}

// ---------------- combined LN: FPC[:,0:256]->XG(ld520), FPC[:,256:384]->T2 ----------------
__global__ void ln_fp(const unsigned short* __restrict__ FPC,
                      const float* __restrict__ g1, const float* __restrict__ be1,
                      const float* __restrict__ g2, const float* __restrict__ be2,
                      unsigned short* __restrict__ XG, unsigned short* __restrict__ T2) {
    int row = blockIdx.x, t = threadIdx.x;
    float v = b2f(FPC[(size_t)row * 384 + t]);
    float s = v, q = v * v;
    for (int o = 32; o; o >>= 1) { s += __shfl_xor(s, o, 64); q += __shfl_xor(q, o, 64); }
    __shared__ float rs[6], rq[6];
    int w = t >> 6;
    if ((t & 63) == 0) { rs[w] = s; rq[w] = q; }
    __syncthreads();
    if (t < 256) {
        float ts = rs[0] + rs[1] + rs[2] + rs[3], tq = rq[0] + rq[1] + rq[2] + rq[3];
        float mean = ts * (1.f / 256.f);
        float var = tq * (1.f / 256.f) - mean * mean;
        float o = (v - mean) * rsqrtf(var + 1e-5f) * g1[t] + be1[t];
        XG[(size_t)row * 520 + t] = f2b(o);
    } else {
        int tt = t - 256;
        float ts = rs[4] + rs[5], tq = rq[4] + rq[5];
        float mean = ts * (1.f / 128.f);
        float var = tq * (1.f / 128.f) - mean * mean;
        float o = (v - mean) * rsqrtf(var + 1e-5f) * g2[tt] + be2[tt];
        T2[(size_t)row * 128 + tt] = f2b(o);
    }
}

// ---------------- attention glue: 2 rows/block, 128 threads ----------------
__global__ __launch_bounds__(128)
void glue_attn(const float* __restrict__ allyf, const float* __restrict__ enemyf,
               const float* __restrict__ ownf, const unsigned short* __restrict__ QKS,
               unsigned short* __restrict__ X) {
    __shared__ float af[2][495];
    __shared__ float ef[2][528];
    __shared__ float qk[2][256];
    __shared__ float attnA[2][64];
    __shared__ float attnE[2][64];
    __shared__ float mskA[2][16];
    __shared__ float mskE[2][16];
    int tid = threadIdx.x;
    size_t rb = (size_t)blockIdx.x * 2;

    for (int idx = tid; idx < 240; idx += 128) {
        int r = idx / 120, w0 = (idx % 120) * 4;
        float4 v = *(const float4*)(allyf + (rb + r) * 480 + w0);
        float* d = &af[r][(w0 >> 5) * 33 + (w0 & 31)];
        d[0] = v.x; d[1] = v.y; d[2] = v.z; d[3] = v.w;
    }
    for (int idx = tid; idx < 256; idx += 128) {
        int r = idx >> 7, w0 = (idx & 127) * 4;
        float4 v = *(const float4*)(enemyf + (rb + r) * 512 + w0);
        float* d = &ef[r][(w0 >> 5) * 33 + (w0 & 31)];
        d[0] = v.x; d[1] = v.y; d[2] = v.z; d[3] = v.w;
    }
    for (int idx = tid; idx < 512; idx += 128)
        qk[idx >> 8][idx & 255] = b2f(QKS[(rb + (idx >> 8)) * 256 + (idx & 255)]);
    if (tid < 64) {
        int r = tid >> 5, c = tid & 31;
        X[(rb + r) * 360 + c] = f2b(ownf[(rb + r) * 32 + c]);
    } else if (tid < 76) {
        int j = tid - 64, r = j / 6, c = 98 + j % 6;
        X[(rb + r) * 360 + c] = 0;
    }
    __syncthreads();

    int r = tid >> 6, lane = tid & 63;
    // masks
    if (lane < 15) {
        bool nz = false;
        for (int d = 0; d < 32; d++) nz |= (af[r][lane * 33 + d] != 0.f);
        mskA[r][lane] = nz ? 1.f : 0.f;
    } else if (lane == 15) {
        mskA[r][15] = 0.f;
    } else if (lane < 32) {
        int mm = lane - 16;
        bool nz = false;
        for (int d = 0; d < 32; d++) nz |= (ef[r][mm * 33 + d] != 0.f);
        mskE[r][mm] = nz ? 1.f : 0.f;
    }
    __syncthreads();

    int h = lane >> 4, m = lane & 15;
    {   // ally softmax
        float sc = -3.0e38f;
        if (m < 15) {
            float s = 0.f;
            for (int d = 0; d < 32; d++) s += qk[r][h * 32 + d] * af[r][m * 33 + d];
            sc = (mskA[r][m] > 0.f) ? s * 0.125f : -1e9f;
        }
        float mx = sc;
        for (int o = 8; o; o >>= 1) mx = fmaxf(mx, __shfl_xor(mx, o, 64));
        float e = (m < 15) ? __expf(sc - mx) : 0.f;
        float sm = e;
        for (int o = 8; o; o >>= 1) sm += __shfl_xor(sm, o, 64);
        attnA[r][h * 16 + m] = e / sm;
    }
    {   // enemy softmax
        float s = 0.f;
        for (int d = 0; d < 32; d++) s += qk[r][128 + h * 32 + d] * ef[r][m * 33 + d];
        float sc = (mskE[r][m] > 0.f) ? s * 0.125f : -1e9f;
        float mx = sc;
        for (int o = 8; o; o >>= 1) mx = fmaxf(mx, __shfl_xor(mx, o, 64));
        float e = __expf(sc - mx);
        float sm = e;
        for (int o = 8; o; o >>= 1) sm += __shfl_xor(sm, o, 64);
        attnE[r][h * 16 + m] = e / sm;
    }
    __syncthreads();
    size_t row = rb + r;
#pragma unroll
    for (int it = 0; it < 2; it++) {
        int idx = lane + it * 64;
        int hh = idx >> 5, c = idx & 31;
        float sA = 0.f;
        for (int mm = 0; mm < 15; mm++) sA += attnA[r][hh * 16 + mm] * af[r][mm * 33 + c];
        X[row * 360 + 104 + idx] = f2b(sA);
        float sE = 0.f;
        for (int mm = 0; mm < 16; mm++) sE += attnE[r][hh * 16 + mm] * ef[r][mm * 33 + c];
        X[row * 360 + 232 + idx] = f2b(sE);
    }
    if (lane < 32) {
        float cnt = 0.f;
        for (int mm = 0; mm < 15; mm++) cnt += mskA[r][mm];
        float s = 0.f;
        for (int mm = 0; mm < 15; mm++) s += af[r][mm * 33 + lane];
        X[row * 360 + 32 + lane] = f2b(s / fmaxf(cnt, 1e-8f));
        if (lane == 0) X[row * 360 + 96] = f2b(cnt > 0.f ? 1.f : 0.f);
    } else {
        int c = lane - 32;
        float cnt = 0.f;
        for (int mm = 0; mm < 16; mm++) cnt += mskE[r][mm];
        float s = 0.f;
        for (int mm = 0; mm < 16; mm++) s += ef[r][mm * 33 + c];
        X[row * 360 + 64 + c] = f2b(s / fmaxf(cnt, 1e-8f));
        if (c == 0) X[row * 360 + 97] = f2b(cnt > 0.f ? 1.f : 0.f);
    }
}

// ---------------- fused LN(128) + role head -> XG cols 256..264 ----------------
__global__ __launch_bounds__(256)
void ln_role(const unsigned short* __restrict__ T3, const float* __restrict__ g1,
             const float* __restrict__ be1, const float* __restrict__ W2,
             const float* __restrict__ b2, const float* __restrict__ rg,
             const float* __restrict__ rb, unsigned short* __restrict__ XG) {
    __shared__ float t3[32][132];
    __shared__ float gl[128], bl[128];
    int tid = threadIdx.x;
    size_t base = (size_t)blockIdx.x * 4096;
    for (int idx = tid; idx < 4096; idx += 256)
        t3[idx >> 7][idx & 127] = b2f(T3[base + idx]);
    if (tid < 128) { gl[tid] = g1[tid]; bl[tid] = be1[tid]; }
    __syncthreads();
    int r = tid >> 3, t = tid & 7;
    float s = 0.f, q = 0.f;
    for (int c = 0; c < 16; c++) { float v = t3[r][t * 16 + c]; s += v; q += v * v; }
    for (int o = 4; o; o >>= 1) { s += __shfl_xor(s, o, 8); q += __shfl_xor(q, o, 8); }
    float mean = s * (1.f / 128.f);
    float var = q * (1.f / 128.f) - mean * mean;
    float rstd = rsqrtf(var + 1e-5f);
    float acc = b2[t];
    const float* w = W2 + t * 128;
    for (int d = 0; d < 128; d++)
        acc += w[d] * ((t3[r][d] - mean) * rstd * gl[d] + bl[d]);
    float v = tanhf(acc);
    float mn = v;
    for (int o = 4; o; o >>= 1) mn += __shfl_xor(mn, o, 8);
    mn *= 0.125f;
    float dv = v - mn, qq = dv * dv;
    for (int o = 4; o; o >>= 1) qq += __shfl_xor(qq, o, 8);
    qq *= 0.125f;
    size_t row = (size_t)blockIdx.x * 32 + r;
    XG[row * 520 + 256 + t] = f2b(dv * rsqrtf(qq + 1e-5f) * rg[t] + rb[t]);
}

// ---------------- merged tail: GRU nonlinearity + qws matvec + final heads ----------------
__global__ __launch_bounds__(320)
void glue_tail(const unsigned short* __restrict__ G, const float* __restrict__ hp,
               const unsigned short* __restrict__ XG, const unsigned short* __restrict__ QWSW,
               const float* __restrict__ enemyf, const float* __restrict__ qnb,
               float* __restrict__ Q, float* __restrict__ Hout) {
    __shared__ float xq[264];
    __shared__ float efs[528];
    __shared__ float qws[40];
    size_t row = blockIdx.x;
    int t = threadIdx.x;
    for (int idx = t; idx < 512; idx += 320)
        efs[(idx >> 5) * 33 + (idx & 31)] = enemyf[row * 512 + idx];
    if (t < 256) {
        size_t b = row * 1024;
        float rg = 1.f / (1.f + __expf(-b2f(G[b + t])));
        float zg = 1.f / (1.f + __expf(-b2f(G[b + 256 + t])));
        float ng = tanhf(b2f(G[b + 512 + t]) + rg * b2f(G[b + 768 + t]));
        float h = (1.f - zg) * ng + zg * hp[row * 256 + t];
        Hout[row * 256 + t] = h;
        xq[t] = h;
    } else if (t < 264) {
        xq[t] = b2f(XG[row * 520 + t]);   // r values (cols 256..263)
    }
    __syncthreads();
    {   // qws[o] = sum_i QWSW[o][i] * xq[i], 8 threads/output
        int o = t >> 3, sub = t & 7;
        const unsigned short* wr = QWSW + o * 264 + sub * 33;
        const float* xv = xq + sub * 33;
        float s = 0.f;
        for (int i = 0; i < 33; i++) s += b2f(wr[i]) * xv[i];
        for (int off = 4; off; off >>= 1) s += __shfl_xor(s, off, 8);
        if (sub == 0) qws[o] = s;
    }
    __syncthreads();
    if (t < 16) {
        const float* fr = efs + t * 33;
        bool nz = false;
        float s = 0.f;
        for (int d = 0; d < 32; d++) { nz |= (fr[d] != 0.f); s += qws[d] * fr[d]; }
        float mk = nz ? 1.f : 0.f;
        float lg = (s + qws[32]) * 0.0625f;
        float sv = mk * lg, cv = mk;
        for (int o = 8; o; o >>= 1) { sv += __shfl_xor(sv, o, 16); cv += __shfl_xor(cv, o, 16); }
        float mean = sv / fmaxf(cv, 1.f);
        Q[row * 22 + 6 + t] = (mk > 0.f ? lg : -1e9f) - mean;
    } else if (t >= 64 && t < 70) {
        int j = t - 64;
        Q[row * 22 + j] = qws[33 + j] + qnb[j];
    }
}

// ---------------- host orchestration ----------------
extern "C" void kernel_launch(void* const* d_in, const int* in_sizes, int n_in,
                              void* d_out, int out_size, void* d_ws, size_t ws_size,
                              hipStream_t stream) {
    const float* own_feats = (const float*)d_in[1];
    const float* ally_feats = (const float*)d_in[2];
    const float* enemy_feats = (const float*)d_in[3];
    const float* hidden = (const float*)d_in[4];
    const float* own_W = (const float*)d_in[5];   const float* own_b = (const float*)d_in[6];
    const float* ally_W = (const float*)d_in[7];  const float* ally_b = (const float*)d_in[8];
    const float* en_W = (const float*)d_in[9];    const float* en_b = (const float*)d_in[10];
    const float* aA_Wq = (const float*)d_in[11];  const float* aA_Wk = (const float*)d_in[12];
    const float* aA_Wv = (const float*)d_in[13];  const float* aA_Wo = (const float*)d_in[14];
    const float* aE_Wq = (const float*)d_in[15];  const float* aE_Wk = (const float*)d_in[16];
    const float* aE_Wv = (const float*)d_in[17];  const float* aE_Wo = (const float*)d_in[18];
    const float* fuse_W1 = (const float*)d_in[19]; const float* fuse_b1 = (const float*)d_in[20];
    const float* fuse_g1 = (const float*)d_in[21]; const float* fuse_be1 = (const float*)d_in[22];
    const float* fuse_W2 = (const float*)d_in[23]; const float* fuse_b2 = (const float*)d_in[24];
    const float* pool_W1 = (const float*)d_in[25]; const float* pool_b1 = (const float*)d_in[26];
    const float* pool_g1 = (const float*)d_in[27]; const float* pool_be1 = (const float*)d_in[28];
    const float* pool_W2 = (const float*)d_in[29]; const float* pool_b2 = (const float*)d_in[30];
    const float* role_W1 = (const float*)d_in[31]; const float* role_b1 = (const float*)d_in[32];
    const float* role_g1 = (const float*)d_in[33]; const float* role_be1 = (const float*)d_in[34];
    const float* role_W2 = (const float*)d_in[35]; const float* role_b2 = (const float*)d_in[36];
    const float* rln_g = (const float*)d_in[37];   const float* rln_b = (const float*)d_in[38];
    const float* gru_Wih = (const float*)d_in[39]; const float* gru_Whh = (const float*)d_in[40];
    const float* gru_bih = (const float*)d_in[41]; const float* gru_bhh = (const float*)d_in[42];
    const float* qn_W = (const float*)d_in[43];    const float* qn_b = (const float*)d_in[44];
    const float* qp_W = (const float*)d_in[45];    const float* kp_W = (const float*)d_in[46];

    char* wsp = (char*)d_ws;
    size_t off = 0;
    auto alloc = [&](size_t bytes) { void* p = wsp + off; off = (off + bytes + 255) & ~(size_t)255; return p; };

    unsigned short* X    = (unsigned short*)alloc((size_t)MROWS * 360 * 2);
    unsigned short* XG   = (unsigned short*)alloc((size_t)MROWS * 520 * 2);
    unsigned short* FPC  = (unsigned short*)alloc((size_t)MROWS * 384 * 2);
    unsigned short* GIb  = (unsigned short*)alloc((size_t)MROWS * 1024 * 2);
    unsigned short* T2b  = (unsigned short*)alloc((size_t)MROWS * 128 * 2);
    unsigned short* T3b  = (unsigned short*)alloc((size_t)MROWS * 128 * 2);
    unsigned short* QKSb = (unsigned short*)alloc((size_t)MROWS * 256 * 2);
    unsigned short* OWNb = (unsigned short*)alloc((size_t)MROWS * 32 * 2);
    // composed bf16 weights
    unsigned short* FPW  = (unsigned short*)alloc(384 * 360 * 2);
    unsigned short* WRZ  = (unsigned short*)alloc(512 * 520 * 2);
    unsigned short* WIN  = (unsigned short*)alloc(256 * 264 * 2);
    unsigned short* WHN  = (unsigned short*)alloc(256 * 256 * 2);
    unsigned short* QWSW = (unsigned short*)alloc(40 * 264 * 2);
    unsigned short* WQKSO= (unsigned short*)alloc(256 * 32 * 2);
    unsigned short* rpW  = (unsigned short*)alloc(128 * 128 * 2);
    unsigned short* zbuf = (unsigned short*)alloc(256);
    // fp32 scratch
    float* WkAp = (float*)alloc(256 * 32 * 4);
    float* WvAp = (float*)alloc(256 * 32 * 4);
    float* WkEp = (float*)alloc(256 * 32 * 4);
    float* WvEp = (float*)alloc(256 * 32 * 4);
    float* Wkpp = (float*)alloc(256 * 32 * 4);
    float* WQKS_AE = (float*)alloc(256 * 256 * 4);
    float* WoVA = (float*)alloc(256 * 128 * 4);
    float* WoVE = (float*)alloc(256 * 128 * 4);
    float* bvAp = (float*)alloc(256 * 4);
    float* bvEp = (float*)alloc(256 * 4);
    float* bkpp = (float*)alloc(256 * 4);
    float* vall = (float*)alloc(768 * 4);
    float* qksb = (float*)alloc(256 * 4);
    float* fpb  = (float*)alloc(384 * 4);
    float* gbias= (float*)alloc(1024 * 4);
    float* rpb  = (float*)alloc(128 * 4);

    float* Qout = (float*)d_out;
    float* Hout = Qout + (size_t)MROWS * 22;

    auto mk = [](int type, const float* A, int sAi, int sAk, const float* B, int sBj, int sBk,
                 void* O, int sOi, int I, int J, int K, int nb = 1, int aB = 0, int bB = 0,
                 int oB = 0, const float* b1 = nullptr, const float* b2 = nullptr) {
        TOp o; o.type = type; o.A = A; o.sAi = sAi; o.sAk = sAk; o.B = B; o.sBj = sBj;
        o.sBk = sBk; o.O = O; o.sOi = sOi; o.I = I; o.J = J; o.K = K; o.nb = nb;
        o.aB = aB; o.bB = bB; o.oB = oB; o.bias1 = b1; o.bias2 = b2; return o;
    };
    auto tilesOf = [](const TOp& o) {
        return o.nb * (((o.I + 31) / 32) * ((o.J + 31) / 32));
    };

    // ---- prep ----
    cvt_misc<<<(MROWS * 64 + MROWS * 8 + 16 + 255) / 256, 256, 0, stream>>>(hidden, own_feats, XG, OWNb, zbuf);

    {   // L1: everything computable from raw inputs
        TOpSet S; S.n = 0; int grid = 0;
        auto add = [&](TOp o) { S.tiles[S.n] = tilesOf(o); grid += S.tiles[S.n]; S.ops[S.n++] = o; };
        add(mk(1, aA_Wk, 256, 1, ally_W, 1, 32, WkAp, 32, 256, 32, 256));
        add(mk(1, aA_Wv, 256, 1, ally_W, 1, 32, WvAp, 32, 256, 32, 256));
        add(mk(1, aE_Wk, 256, 1, en_W, 1, 32, WkEp, 32, 256, 32, 256));
        add(mk(1, aE_Wv, 256, 1, en_W, 1, 32, WvEp, 32, 256, 32, 256));
        add(mk(1, kp_W, 256, 1, en_W, 1, 32, Wkpp, 32, 256, 32, 256));
        add(mk(1, aA_Wv, 256, 1, ally_b, 0, 1, bvAp, 1, 256, 1, 256));
        add(mk(1, aE_Wv, 256, 1, en_b, 0, 1, bvEp, 1, 256, 1, 256));
        add(mk(1, kp_W, 256, 1, en_b, 0, 1, bkpp, 1, 256, 1, 256));
        add(mk(4, own_b, 1, 1, nullptr, 0, 0, vall, 1, 256, 1, 0));
        add(mk(1, role_W1, 128, 1, pool_b2, 0, 1, rpb, 1, 128, 1, 128, 1, 0, 0, 0, role_b1));
        add(mk(1, gru_Wih, 264, 1, fuse_b2, 0, 1, gbias, 1, 512, 1, 256, 1, 0, 0, 0, gru_bih, gru_bhh));
        add(mk(1, gru_Wih + 512 * 264, 264, 1, fuse_b2, 0, 1, gbias + 512, 1, 256, 1, 256, 1, 0, 0, 0, gru_bih + 512));
        add(mk(4, gru_bhh + 512, 1, 1, nullptr, 0, 0, gbias + 768, 1, 256, 1, 0));
        compose_tiled<<<grid, 256, 0, stream>>>(S);
    }
    {   // L2: per-head QK compose, Wo@Wv, ctx bias halves
        TOpSet S; S.n = 0; int grid = 0;
        auto add = [&](TOp o) { S.tiles[S.n] = tilesOf(o); grid += S.tiles[S.n]; S.ops[S.n++] = o; };
        add(mk(1, WkAp, 1, 32, aA_Wq, 1, 256, WQKS_AE, 256, 32, 256, 64, 4, 2048, 16384, 8192));
        add(mk(1, WkEp, 1, 32, aE_Wq, 1, 256, WQKS_AE + 128 * 256, 256, 32, 256, 64, 4, 2048, 16384, 8192));
        add(mk(1, aA_Wo, 256, 1, WvAp, 1, 32, WoVA, 128, 256, 32, 64, 4, 64, 2048, 32));
        add(mk(1, aE_Wo, 256, 1, WvEp, 1, 32, WoVE, 128, 256, 32, 64, 4, 64, 2048, 32));
        add(mk(1, aA_Wo, 256, 1, bvAp, 0, 1, vall + 256, 1, 256, 1, 256));
        add(mk(1, aE_Wo, 256, 1, bvEp, 0, 1, vall + 512, 1, 256, 1, 256));
        compose_tiled<<<grid, 256, 0, stream>>>(S);
    }
    {   // L3: final composed weights + biases
        TOpSet S; S.n = 0; int grid = 0;
        auto add = [&](TOp o) { S.tiles[S.n] = tilesOf(o); grid += S.tiles[S.n]; S.ops[S.n++] = o; };
        add(mk(1, WQKS_AE, 256, 1, own_b, 0, 1, qksb, 1, 256, 1, 256));
        add(mk(1, fuse_W1, 768, 1, vall, 0, 1, fpb, 1, 256, 1, 768, 1, 0, 0, 0, fuse_b1));
        add(mk(1, pool_W1, 768, 1, own_b, 0, 1, fpb + 256, 1, 128, 1, 256, 1, 0, 0, 0, pool_b1));
        add(mk(0, WQKS_AE, 256, 1, own_W, 1, 32, WQKSO, 32, 256, 32, 256));
        // FPW fuse rows
        add(mk(0, fuse_W1, 768, 1, own_W, 1, 32, FPW, 360, 256, 32, 256));
        add(mk(3, nullptr, 0, 0, nullptr, 0, 0, FPW + 32, 360, 256, 72, 0));
        add(mk(0, fuse_W1 + 256, 768, 1, WoVA, 1, 128, FPW + 104, 360, 256, 128, 256));
        add(mk(0, fuse_W1 + 512, 768, 1, WoVE, 1, 128, FPW + 232, 360, 256, 128, 256));
        // FPW pool rows
        add(mk(0, pool_W1, 768, 1, own_W, 1, 32, FPW + 256 * 360, 360, 128, 32, 256));
        add(mk(0, pool_W1 + 256, 768, 1, ally_W, 1, 32, FPW + 256 * 360 + 32, 360, 128, 32, 256));
        add(mk(0, pool_W1 + 512, 768, 1, en_W, 1, 32, FPW + 256 * 360 + 64, 360, 128, 32, 256));
        add(mk(0, pool_W1 + 256, 768, 1, ally_b, 0, 1, FPW + 256 * 360 + 96, 360, 128, 1, 256));
        add(mk(0, pool_W1 + 512, 768, 1, en_b, 0, 1, FPW + 256 * 360 + 97, 360, 128, 1, 256));
        add(mk(3, nullptr, 0, 0, nullptr, 0, 0, FPW + 256 * 360 + 98, 360, 128, 262, 0));
        // WRZ
        add(mk(0, gru_Wih, 264, 1, fuse_W2, 1, 256, WRZ, 520, 512, 256, 256));
        add(mk(2, gru_Wih + 256, 264, 1, nullptr, 0, 0, WRZ + 256, 520, 512, 8, 0));
        add(mk(2, gru_Whh, 256, 1, nullptr, 0, 0, WRZ + 264, 520, 512, 256, 0));
        // WIN
        add(mk(0, gru_Wih + 512 * 264, 264, 1, fuse_W2, 1, 256, WIN, 264, 256, 256, 256));
        add(mk(2, gru_Wih + 512 * 264 + 256, 264, 1, nullptr, 0, 0, WIN + 256, 264, 256, 8, 0));
        // WHN
        add(mk(2, gru_Whh + 512 * 256, 256, 1, nullptr, 0, 0, WHN, 256, 256, 256, 0));
        // QWSW
        add(mk(0, Wkpp, 1, 32, qp_W, 1, 264, QWSW, 264, 32, 264, 256));
        add(mk(0, bkpp, 0, 1, qp_W, 1, 264, QWSW + 32 * 264, 264, 1, 264, 256));
        add(mk(2, qn_W, 256, 1, nullptr, 0, 0, QWSW + 33 * 264, 264, 6, 256, 0));
        add(mk(3, nullptr, 0, 0, nullptr, 0, 0, QWSW + 33 * 264 + 256, 264, 6, 8, 0));
        add(mk(3, nullptr, 0, 0, nullptr, 0, 0, QWSW + 39 * 264, 264, 1, 264, 0));
        // rpW
        add(mk(0, role_W1, 128, 1, pool_W2, 1, 128, rpW, 128, 128, 128, 128));
        compose_tiled<<<grid, 256, 0, stream>>>(S);
    }

    auto gemm = [&](const unsigned short* A, int lda, const unsigned short* Wm, const float* bias,
                    unsigned short* C, int ldc, int N, int K, int act) {
        gemm_bf16<<<dim3(N / 128, MROWS / 128), 256, 0, stream>>>(A, lda, Wm, bias, C, ldc, N, K, act, zbuf);
    };

    // ---- main chain ----
    gemm(OWNb, 32, WQKSO, qksb, QKSb, 256, 256, 32, 0);                  // QKS
    glue_attn<<<MROWS / 2, 128, 0, stream>>>(ally_feats, enemy_feats, own_feats, QKSb, X);
    gemm(X, 360, FPW, fpb, FPC, 384, 384, 360, 1);                       // fuse1+pool1 (+gelu)
    ln_fp<<<MROWS, 384, 0, stream>>>(FPC, fuse_g1, fuse_be1, pool_g1, pool_be1, XG, T2b);
    gemm(T2b, 128, rpW, rpb, T3b, 128, 128, 128, 1);                     // role1 (pool_W2 folded)
    ln_role<<<MROWS / 32, 256, 0, stream>>>(T3b, role_g1, role_be1, role_W2, role_b2, rln_g, rln_b, XG);
    gemm(XG, 520, WRZ, gbias, GIb, 1024, 512, 520, 0);                   // r,z (i+h pre-summed)
    gemm(XG, 520, WIN, gbias + 512, GIb + 512, 1024, 256, 264, 0);       // i_n
    gemm(XG + 264, 520, WHN, gbias + 768, GIb + 768, 1024, 256, 256, 0); // h_n
    glue_tail<<<MROWS, 320, 0, stream>>>(GIb, hidden, XG, QWSW, enemy_feats, qn_b, Qout, Hout);
}

// Round 6
// 505.314 us; speedup vs baseline: 1.1868x; 1.1868x over previous
//
#include <hip/hip_runtime.h>
#include <hip/hip_bf16.h>

// CAPERNN_ContRoles_HPN — round 6: revert tail + glue_attn to round-4 proven forms;
// keep n-fast grid & split GRU (merged into ONE gemm_gru dispatch); cvt folded into L1.
// M = BN = 16384, H=256, NH=4, HD=64, NA=15, NE=16, RD=8, NMOVE=6.

#define MROWS 16384

typedef __attribute__((ext_vector_type(8))) short short8;
typedef __attribute__((ext_vector_type(4))) float float4v;

__device__ __forceinline__ unsigned short f2b(float f) {
    __hip_bfloat16 h = __float2bfloat16(f);
    return *reinterpret_cast<unsigned short*>(&h);
}
__device__ __forceinline__ float b2f(unsigned short u) {
    __hip_bfloat16 h;
    *reinterpret_cast<unsigned short*>(&h) = u;
    return __bfloat162float(h);
}
__device__ __forceinline__ void gll16(const unsigned short* g, unsigned short* l) {
    __builtin_amdgcn_global_load_lds((const __attribute__((address_space(1))) void*)g,
                                     (__attribute__((address_space(3))) void*)l, 16, 0, 0);
}

// ---------------- tiled compose ----------------
// type 0: matmul->bf16, 1: matmul->fp32, 2: cvt copy->bf16, 3: zero bf16, 4: copy fp32
struct TOp {
    int type;
    const float* A; int sAi, sAk;
    const float* B; int sBj, sBk;
    void* O; int sOi;
    int I, J, K;
    int nb; int aB, bB, oB;
    const float* bias1; const float* bias2;
};
struct TOpSet { int n; int tiles[26]; TOp ops[26]; };

__global__ __launch_bounds__(256)
void compose_tiled(TOpSet S) {
    int t = blockIdx.x;
    int op = 0;
    while (op < S.n && t >= S.tiles[op]) { t -= S.tiles[op]; op++; }
    if (op >= S.n) return;
    TOp o = S.ops[op];
    int ti = (o.I + 31) >> 5, tj = (o.J + 31) >> 5;
    int per = ti * tj;
    int b = t / per;
    int rem = t - b * per;
    int i0 = (rem / tj) * 32, j0 = (rem % tj) * 32;
    int tid = threadIdx.x;
    if (o.type >= 2) {
        for (int e = tid; e < 1024; e += 256) {
            int r = e >> 5, c = e & 31;
            int i = i0 + r, j = j0 + c;
            if (i < o.I && j < o.J) {
                long oidx = (long)b * o.oB + (long)i * o.sOi + j;
                if (o.type == 3) { ((unsigned short*)o.O)[oidx] = 0; }
                else {
                    float v = o.A[(long)b * o.aB + (long)i * o.sAi + (long)j * o.sAk];
                    if (o.type == 2) ((unsigned short*)o.O)[oidx] = f2b(v);
                    else ((float*)o.O)[oidx] = v;
                }
            }
        }
        return;
    }
    __shared__ float As[32][33];
    __shared__ float Bs[32][33];
    int tx = tid & 15, ty = tid >> 4;
    float a00 = 0.f, a01 = 0.f, a10 = 0.f, a11 = 0.f;
    const float* Ab = o.A + (long)b * o.aB;
    const float* Bb = o.B + (long)b * o.bB;
    for (int k0 = 0; k0 < o.K; k0 += 32) {
        for (int e = tid; e < 1024; e += 256) {
            int r = e >> 5, c = e & 31;
            As[r][c] = (i0 + r < o.I && k0 + c < o.K)
                       ? Ab[(long)(i0 + r) * o.sAi + (long)(k0 + c) * o.sAk] : 0.f;
            Bs[r][c] = (k0 + r < o.K && j0 + c < o.J)
                       ? Bb[(long)(j0 + c) * o.sBj + (long)(k0 + r) * o.sBk] : 0.f;
        }
        __syncthreads();
#pragma unroll
        for (int k = 0; k < 32; k++) {
            float x0 = As[ty * 2][k], x1 = As[ty * 2 + 1][k];
            float y0 = Bs[k][tx * 2], y1 = Bs[k][tx * 2 + 1];
            a00 += x0 * y0; a01 += x0 * y1; a10 += x1 * y0; a11 += x1 * y1;
        }
        __syncthreads();
    }
    int i = i0 + ty * 2, j = j0 + tx * 2;
    float vals[2][2] = {{a00, a01}, {a10, a11}};
#pragma unroll
    for (int di = 0; di < 2; di++)
#pragma unroll
        for (int dj = 0; dj < 2; dj++) {
            int ii = i + di, jj = j + dj;
            if (ii < o.I && jj < o.J) {
                float v = vals[di][dj];
                if (o.bias1) v += o.bias1[ii];
                if (o.bias2) v += o.bias2[ii];
                long oidx = (long)b * o.oB + (long)ii * o.sOi + jj;
                if (o.type == 0) ((unsigned short*)o.O)[oidx] = f2b(v);
                else ((float*)o.O)[oidx] = v;
            }
        }
}

// ---------------- bf16 MFMA GEMM (n-fast grid, guarded): C = A @ W^T (+bias)(+gelu) ----------------
__global__ __launch_bounds__(256, 4)
void gemm_bf16(const unsigned short* __restrict__ A, int lda,
               const unsigned short* __restrict__ W,
               const float* __restrict__ bias,
               unsigned short* __restrict__ C, int ldc,
               int N, int K, int act,
               const unsigned short* __restrict__ zbuf) {
    __shared__ __align__(16) unsigned short As[128 * 32];
    __shared__ __align__(16) unsigned short Bs[128 * 32];
    int tid = threadIdx.x;
    int n0 = blockIdx.x * 128, m0 = blockIdx.y * 128;
    int wave = tid >> 6, lane = tid & 63;
    int wm = (wave & 1) * 64, wn = (wave >> 1) * 64;
    int l16 = lane & 15, quad = lane >> 4;

    float4v acc[4][4];
#pragma unroll
    for (int i = 0; i < 4; i++)
#pragma unroll
        for (int j = 0; j < 4; j++) acc[i][j] = (float4v){0.f, 0.f, 0.f, 0.f};

    int s0 = tid, s1 = tid + 256;
    int row0 = s0 >> 2, seg0 = (s0 & 3) * 8;
    int row1 = s1 >> 2, seg1 = (s1 & 3) * 8;
    const unsigned short* Arow0 = A + (size_t)(m0 + row0) * lda;
    const unsigned short* Arow1 = A + (size_t)(m0 + row1) * lda;
    const unsigned short* Wrow0 = (n0 + row0 < N) ? W + (size_t)(n0 + row0) * K : zbuf;
    const unsigned short* Wrow1 = (n0 + row1 < N) ? W + (size_t)(n0 + row1) * K : zbuf;
    bool wv0 = (n0 + row0 < N), wv1 = (n0 + row1 < N);
    unsigned short* ldsA0 = As + (size_t)(wave * 64) * 8;
    unsigned short* ldsA1 = As + (size_t)(wave * 64 + 256) * 8;
    unsigned short* ldsB0 = Bs + (size_t)(wave * 64) * 8;
    unsigned short* ldsB1 = Bs + (size_t)(wave * 64 + 256) * 8;

    for (int k0 = 0; k0 < K; k0 += 32) {
        int ka0 = k0 + seg0, ka1 = k0 + seg1;
        gll16((ka0 < K) ? Arow0 + ka0 : zbuf, ldsA0);
        gll16((ka1 < K) ? Arow1 + ka1 : zbuf, ldsA1);
        gll16((ka0 < K && wv0) ? Wrow0 + ka0 : zbuf, ldsB0);
        gll16((ka1 < K && wv1) ? Wrow1 + ka1 : zbuf, ldsB1);
        __syncthreads();
        short8 a[4], b[4];
#pragma unroll
        for (int i = 0; i < 4; i++) {
            a[i] = *(const short8*)(&As[(wm + i * 16 + l16) * 32 + quad * 8]);
            b[i] = *(const short8*)(&Bs[(wn + i * 16 + l16) * 32 + quad * 8]);
        }
#pragma unroll
        for (int i = 0; i < 4; i++)
#pragma unroll
            for (int j = 0; j < 4; j++)
                acc[i][j] = __builtin_amdgcn_mfma_f32_16x16x32_bf16(a[i], b[j], acc[i][j], 0, 0, 0);
        __syncthreads();
    }
#pragma unroll
    for (int i = 0; i < 4; i++) {
#pragma unroll
        for (int j = 0; j < 4; j++) {
#pragma unroll
            for (int rr = 0; rr < 4; rr++) {
                int rowm = m0 + wm + i * 16 + quad * 4 + rr;
                int coln = wn + j * 16 + l16;
                if (n0 + coln >= N) continue;
                float v = acc[i][j][rr];
                if (bias) v += bias[n0 + coln];
                if (act == 1) v = 0.5f * v * (1.f + erff(v * 0.70710678f));
                C[(size_t)rowm * ldc + n0 + coln] = f2b(v);
            }
        }
    }
}

// ---------------- merged GRU GEMM: one dispatch, 3 weight segments -> GIb[1024 cols] ----------------
// bx 0..3: RZ (K=520, A=XG), bx 4..5: IN (K=264, A=XG), bx 6..7: HN (K=256, A=XG+264)
__global__ __launch_bounds__(256, 4)
void gemm_gru(const unsigned short* __restrict__ XG,
              const unsigned short* __restrict__ WRZ, const unsigned short* __restrict__ WIN,
              const unsigned short* __restrict__ WHN, const float* __restrict__ gbias,
              unsigned short* __restrict__ GIb, const unsigned short* __restrict__ zbuf) {
    __shared__ __align__(16) unsigned short As[128 * 32];
    __shared__ __align__(16) unsigned short Bs[128 * 32];
    int tid = threadIdx.x;
    int bx = blockIdx.x, m0 = blockIdx.y * 128;
    int seg = (bx < 4) ? 0 : (bx < 6 ? 1 : 2);
    int K = (seg == 0) ? 520 : (seg == 1 ? 264 : 256);
    const unsigned short* A = (seg == 2) ? XG + 264 : XG;
    const unsigned short* W = (seg == 0) ? WRZ + (size_t)(bx * 128) * 520
                            : (seg == 1) ? WIN + (size_t)((bx - 4) * 128) * 264
                                         : WHN + (size_t)((bx - 6) * 128) * 256;
    int cb = bx * 128;
    int wave = tid >> 6, lane = tid & 63;
    int wm = (wave & 1) * 64, wn = (wave >> 1) * 64;
    int l16 = lane & 15, quad = lane >> 4;

    float4v acc[4][4];
#pragma unroll
    for (int i = 0; i < 4; i++)
#pragma unroll
        for (int j = 0; j < 4; j++) acc[i][j] = (float4v){0.f, 0.f, 0.f, 0.f};

    int s0 = tid, s1 = tid + 256;
    int row0 = s0 >> 2, seg0 = (s0 & 3) * 8;
    int row1 = s1 >> 2, seg1 = (s1 & 3) * 8;
    const unsigned short* Arow0 = A + (size_t)(m0 + row0) * 520;
    const unsigned short* Arow1 = A + (size_t)(m0 + row1) * 520;
    const unsigned short* Wrow0 = W + (size_t)row0 * K;
    const unsigned short* Wrow1 = W + (size_t)row1 * K;
    unsigned short* ldsA0 = As + (size_t)(wave * 64) * 8;
    unsigned short* ldsA1 = As + (size_t)(wave * 64 + 256) * 8;
    unsigned short* ldsB0 = Bs + (size_t)(wave * 64) * 8;
    unsigned short* ldsB1 = Bs + (size_t)(wave * 64 + 256) * 8;

    for (int k0 = 0; k0 < K; k0 += 32) {
        int ka0 = k0 + seg0, ka1 = k0 + seg1;
        gll16((ka0 < K) ? Arow0 + ka0 : zbuf, ldsA0);
        gll16((ka1 < K) ? Arow1 + ka1 : zbuf, ldsA1);
        gll16((ka0 < K) ? Wrow0 + ka0 : zbuf, ldsB0);
        gll16((ka1 < K) ? Wrow1 + ka1 : zbuf, ldsB1);
        __syncthreads();
        short8 a[4], b[4];
#pragma unroll
        for (int i = 0; i < 4; i++) {
            a[i] = *(const short8*)(&As[(wm + i * 16 + l16) * 32 + quad * 8]);
            b[i] = *(const short8*)(&Bs[(wn + i * 16 + l16) * 32 + quad * 8]);
        }
#pragma unroll
        for (int i = 0; i < 4; i++)
#pragma unroll
            for (int j = 0; j < 4; j++)
                acc[i][j] = __builtin_amdgcn_mfma_f32_16x16x32_bf16(a[i], b[j], acc[i][j], 0, 0, 0);
        __syncthreads();
    }
#pragma unroll
    for (int i = 0; i < 4; i++) {
#pragma unroll
        for (int j = 0; j < 4; j++) {
#pragma unroll
            for (int rr = 0; rr < 4; rr++) {
                int rowm = m0 + wm + i * 16 + quad * 4 + rr;
                int coln = cb + wn + j * 16 + l16;
                float v = acc[i][j][rr] + gbias[coln];
                GIb[(size_t)rowm * 1024 + coln] = f2b(v);
            }
        }
    }
}

// ---------------- combined LN: FPC[:,0:256]->XG(ld520), FPC[:,256:384]->T2 ----------------
__global__ void ln_fp(const unsigned short* __restrict__ FPC,
                      const float* __restrict__ g1, const float* __restrict__ be1,
                      const float* __restrict__ g2, const float* __restrict__ be2,
                      unsigned short* __restrict__ XG, unsigned short* __restrict__ T2) {
    int row = blockIdx.x, t = threadIdx.x;
    float v = b2f(FPC[(size_t)row * 384 + t]);
    float s = v, q = v * v;
    for (int o = 32; o; o >>= 1) { s += __shfl_xor(s, o, 64); q += __shfl_xor(q, o, 64); }
    __shared__ float rs[6], rq[6];
    int w = t >> 6;
    if ((t & 63) == 0) { rs[w] = s; rq[w] = q; }
    __syncthreads();
    if (t < 256) {
        float ts = rs[0] + rs[1] + rs[2] + rs[3], tq = rq[0] + rq[1] + rq[2] + rq[3];
        float mean = ts * (1.f / 256.f);
        float var = tq * (1.f / 256.f) - mean * mean;
        float o = (v - mean) * rsqrtf(var + 1e-5f) * g1[t] + be1[t];
        XG[(size_t)row * 520 + t] = f2b(o);
    } else {
        int tt = t - 256;
        float ts = rs[4] + rs[5], tq = rq[4] + rq[5];
        float mean = ts * (1.f / 128.f);
        float var = tq * (1.f / 128.f) - mean * mean;
        float o = (v - mean) * rsqrtf(var + 1e-5f) * g2[tt] + be2[tt];
        T2[(size_t)row * 128 + tt] = f2b(o);
    }
}

// ---------------- attention glue: 4 rows/block, 256 threads (round-4 proven) ----------------
__global__ __launch_bounds__(256)
void glue_attn(const float* __restrict__ allyf, const float* __restrict__ enemyf,
               const float* __restrict__ ownf, const unsigned short* __restrict__ QKS,
               unsigned short* __restrict__ X) {
    __shared__ float af[4][495];
    __shared__ float ef[4][528];
    __shared__ float qk[4][256];
    __shared__ float attnA[4][64];
    __shared__ float attnE[4][64];
    __shared__ float mskA[4][16];
    __shared__ float mskE[4][16];
    int tid = threadIdx.x;
    size_t rb = (size_t)blockIdx.x * 4;

    for (int idx = tid; idx < 480; idx += 256) {
        int r = idx / 120, w0 = (idx % 120) * 4;
        float4 v = *(const float4*)(allyf + (rb + r) * 480 + w0);
        float* d = &af[r][(w0 >> 5) * 33 + (w0 & 31)];
        d[0] = v.x; d[1] = v.y; d[2] = v.z; d[3] = v.w;
    }
    for (int idx = tid; idx < 512; idx += 256) {
        int r = idx >> 7, w0 = (idx & 127) * 4;
        float4 v = *(const float4*)(enemyf + (rb + r) * 512 + w0);
        float* d = &ef[r][(w0 >> 5) * 33 + (w0 & 31)];
        d[0] = v.x; d[1] = v.y; d[2] = v.z; d[3] = v.w;
    }
    for (int idx = tid; idx < 1024; idx += 256)
        qk[idx >> 8][idx & 255] = b2f(QKS[(rb + (idx >> 8)) * 256 + (idx & 255)]);
    if (tid < 128) {
        int r = tid >> 5, c = tid & 31;
        X[(rb + r) * 360 + c] = f2b(ownf[(rb + r) * 32 + c]);
    } else if (tid < 152) {
        int j = tid - 128, r = j / 6, c = 98 + j % 6;
        X[(rb + r) * 360 + c] = 0;
    }
    __syncthreads();

    {
        int r = tid >> 6, lane = tid & 63;
        if (lane < 15) {
            bool nz = false;
            for (int d = 0; d < 32; d++) nz |= (af[r][lane * 33 + d] != 0.f);
            mskA[r][lane] = nz ? 1.f : 0.f;
        } else if (lane == 15) {
            mskA[r][15] = 0.f;
        } else if (lane < 32) {
            int mm = lane - 16;
            bool nz = false;
            for (int d = 0; d < 32; d++) nz |= (ef[r][mm * 33 + d] != 0.f);
            mskE[r][mm] = nz ? 1.f : 0.f;
        }
    }
    __syncthreads();

    int r = tid >> 6, lane = tid & 63;
    int h = lane >> 4, m = lane & 15;
    {   // ally softmax (15 entities)
        float sc = -3.0e38f;
        if (m < 15) {
            float s = 0.f;
            for (int d = 0; d < 32; d++) s += qk[r][h * 32 + d] * af[r][m * 33 + d];
            sc = (mskA[r][m] > 0.f) ? s * 0.125f : -1e9f;
        }
        float mx = sc;
        for (int o = 8; o; o >>= 1) mx = fmaxf(mx, __shfl_xor(mx, o, 64));
        float e = (m < 15) ? __expf(sc - mx) : 0.f;
        float sm = e;
        for (int o = 8; o; o >>= 1) sm += __shfl_xor(sm, o, 64);
        attnA[r][h * 16 + m] = e / sm;
    }
    {   // enemy softmax (16 entities)
        float s = 0.f;
        for (int d = 0; d < 32; d++) s += qk[r][128 + h * 32 + d] * ef[r][m * 33 + d];
        float sc = (mskE[r][m] > 0.f) ? s * 0.125f : -1e9f;
        float mx = sc;
        for (int o = 8; o; o >>= 1) mx = fmaxf(mx, __shfl_xor(mx, o, 64));
        float e = __expf(sc - mx);
        float sm = e;
        for (int o = 8; o; o >>= 1) sm += __shfl_xor(sm, o, 64);
        attnE[r][h * 16 + m] = e / sm;
    }
    __syncthreads();
    size_t row = rb + r;
#pragma unroll
    for (int it = 0; it < 2; it++) {
        int idx = lane + it * 64;
        int hh = idx >> 5, c = idx & 31;
        float sA = 0.f;
        for (int mm = 0; mm < 15; mm++) sA += attnA[r][hh * 16 + mm] * af[r][mm * 33 + c];
        X[row * 360 + 104 + idx] = f2b(sA);
        float sE = 0.f;
        for (int mm = 0; mm < 16; mm++) sE += attnE[r][hh * 16 + mm] * ef[r][mm * 33 + c];
        X[row * 360 + 232 + idx] = f2b(sE);
    }
    if (lane < 32) {
        float cnt = 0.f;
        for (int mm = 0; mm < 15; mm++) cnt += mskA[r][mm];
        float s = 0.f;
        for (int mm = 0; mm < 15; mm++) s += af[r][mm * 33 + lane];
        X[row * 360 + 32 + lane] = f2b(s / fmaxf(cnt, 1e-8f));
        if (lane == 0) X[row * 360 + 96] = f2b(cnt > 0.f ? 1.f : 0.f);
    } else {
        int c = lane - 32;
        float cnt = 0.f;
        for (int mm = 0; mm < 16; mm++) cnt += mskE[r][mm];
        float s = 0.f;
        for (int mm = 0; mm < 16; mm++) s += ef[r][mm * 33 + c];
        X[row * 360 + 64 + c] = f2b(s / fmaxf(cnt, 1e-8f));
        if (c == 0) X[row * 360 + 97] = f2b(cnt > 0.f ? 1.f : 0.f);
    }
}

// ---------------- fused LN(128) + role head -> XG cols 256..264 ----------------
__global__ __launch_bounds__(256)
void ln_role(const unsigned short* __restrict__ T3, const float* __restrict__ g1,
             const float* __restrict__ be1, const float* __restrict__ W2,
             const float* __restrict__ b2, const float* __restrict__ rg,
             const float* __restrict__ rb, unsigned short* __restrict__ XG) {
    __shared__ float t3[32][132];
    __shared__ float gl[128], bl[128];
    int tid = threadIdx.x;
    size_t base = (size_t)blockIdx.x * 4096;
    for (int idx = tid; idx < 4096; idx += 256)
        t3[idx >> 7][idx & 127] = b2f(T3[base + idx]);
    if (tid < 128) { gl[tid] = g1[tid]; bl[tid] = be1[tid]; }
    __syncthreads();
    int r = tid >> 3, t = tid & 7;
    float s = 0.f, q = 0.f;
    for (int c = 0; c < 16; c++) { float v = t3[r][t * 16 + c]; s += v; q += v * v; }
    for (int o = 4; o; o >>= 1) { s += __shfl_xor(s, o, 8); q += __shfl_xor(q, o, 8); }
    float mean = s * (1.f / 128.f);
    float var = q * (1.f / 128.f) - mean * mean;
    float rstd = rsqrtf(var + 1e-5f);
    float acc = b2[t];
    const float* w = W2 + t * 128;
    for (int d = 0; d < 128; d++)
        acc += w[d] * ((t3[r][d] - mean) * rstd * gl[d] + bl[d]);
    float v = tanhf(acc);
    float mn = v;
    for (int o = 4; o; o >>= 1) mn += __shfl_xor(mn, o, 8);
    mn *= 0.125f;
    float dv = v - mn, qq = dv * dv;
    for (int o = 4; o; o >>= 1) qq += __shfl_xor(qq, o, 8);
    qq *= 0.125f;
    size_t row = (size_t)blockIdx.x * 32 + r;
    XG[row * 520 + 256 + t] = f2b(dv * rsqrtf(qq + 1e-5f) * rg[t] + rb[t]);
}

// ---------------- GRU glue (round-4: elementwise, no barriers) ----------------
__global__ void glue_gru(const unsigned short* __restrict__ G, const float* __restrict__ hp,
                         float* __restrict__ hout, unsigned short* __restrict__ XQ,
                         const unsigned short* __restrict__ XG) {
    size_t row = blockIdx.x;
    int i = threadIdx.x;
    size_t b = row * 1024;
    float rg = 1.f / (1.f + __expf(-b2f(G[b + i])));
    float zg = 1.f / (1.f + __expf(-b2f(G[b + 256 + i])));
    float ng = tanhf(b2f(G[b + 512 + i]) + rg * b2f(G[b + 768 + i]));
    float h = (1.f - zg) * ng + zg * hp[row * 256 + i];
    hout[row * 256 + i] = h;
    XQ[row * 264 + i] = f2b(h);
    if (i < 8) XQ[row * 264 + 256 + i] = XG[row * 520 + 256 + i];
}

// ---------------- final heads (round-4) ----------------
__global__ __launch_bounds__(256)
void glue_final(const unsigned short* __restrict__ QWS, const float* __restrict__ efeats,
                const float* __restrict__ qnb, float* __restrict__ Q) {
    __shared__ float ef[8][528];
    __shared__ float qw[8][40];
    int tid = threadIdx.x;
    size_t rb = (size_t)blockIdx.x * 8;
    for (int idx = tid; idx < 1024; idx += 256) {
        int r = idx >> 7, w0 = (idx & 127) * 4;
        float4 v = *(const float4*)(efeats + (rb + r) * 512 + w0);
        float* d = &ef[r][(w0 >> 5) * 33 + (w0 & 31)];
        d[0] = v.x; d[1] = v.y; d[2] = v.z; d[3] = v.w;
    }
    for (int idx = tid; idx < 320; idx += 256) {
        int r = idx / 40, c = idx % 40;
        qw[r][c] = b2f(QWS[(rb + r) * 40 + c]);
    }
    __syncthreads();
    int r = tid >> 5, t = tid & 31;
    size_t row = rb + r;
    float lg = 0.f, mk = 0.f;
    if (t < 16) {
        const float* fr = ef[r] + t * 33;
        bool nz = false;
        float s = 0.f;
        for (int d = 0; d < 32; d++) { nz |= (fr[d] != 0.f); s += qw[r][d] * fr[d]; }
        mk = nz ? 1.f : 0.f;
        lg = (s + qw[r][32]) * 0.0625f;
    }
    float sv = mk * lg, cv = mk;
    for (int o = 8; o; o >>= 1) { sv += __shfl_xor(sv, o, 64); cv += __shfl_xor(cv, o, 64); }
    float mean = sv / fmaxf(cv, 1.f);
    if (t < 16) Q[row * 22 + 6 + t] = (mk > 0.f ? lg : -1e9f) - mean;
    if (t < 6) Q[row * 22 + t] = qw[r][33 + t] + qnb[t];
}

// ---------------- host orchestration ----------------
extern "C" void kernel_launch(void* const* d_in, const int* in_sizes, int n_in,
                              void* d_out, int out_size, void* d_ws, size_t ws_size,
                              hipStream_t stream) {
    const float* own_feats = (const float*)d_in[1];
    const float* ally_feats = (const float*)d_in[2];
    const float* enemy_feats = (const float*)d_in[3];
    const float* hidden = (const float*)d_in[4];
    const float* own_W = (const float*)d_in[5];   const float* own_b = (const float*)d_in[6];
    const float* ally_W = (const float*)d_in[7];  const float* ally_b = (const float*)d_in[8];
    const float* en_W = (const float*)d_in[9];    const float* en_b = (const float*)d_in[10];
    const float* aA_Wq = (const float*)d_in[11];  const float* aA_Wk = (const float*)d_in[12];
    const float* aA_Wv = (const float*)d_in[13];  const float* aA_Wo = (const float*)d_in[14];
    const float* aE_Wq = (const float*)d_in[15];  const float* aE_Wk = (const float*)d_in[16];
    const float* aE_Wv = (const float*)d_in[17];  const float* aE_Wo = (const float*)d_in[18];
    const float* fuse_W1 = (const float*)d_in[19]; const float* fuse_b1 = (const float*)d_in[20];
    const float* fuse_g1 = (const float*)d_in[21]; const float* fuse_be1 = (const float*)d_in[22];
    const float* fuse_W2 = (const float*)d_in[23]; const float* fuse_b2 = (const float*)d_in[24];
    const float* pool_W1 = (const float*)d_in[25]; const float* pool_b1 = (const float*)d_in[26];
    const float* pool_g1 = (const float*)d_in[27]; const float* pool_be1 = (const float*)d_in[28];
    const float* pool_W2 = (const float*)d_in[29]; const float* pool_b2 = (const float*)d_in[30];
    const float* role_W1 = (const float*)d_in[31]; const float* role_b1 = (const float*)d_in[32];
    const float* role_g1 = (const float*)d_in[33]; const float* role_be1 = (const float*)d_in[34];
    const float* role_W2 = (const float*)d_in[35]; const float* role_b2 = (const float*)d_in[36];
    const float* rln_g = (const float*)d_in[37];   const float* rln_b = (const float*)d_in[38];
    const float* gru_Wih = (const float*)d_in[39]; const float* gru_Whh = (const float*)d_in[40];
    const float* gru_bih = (const float*)d_in[41]; const float* gru_bhh = (const float*)d_in[42];
    const float* qn_W = (const float*)d_in[43];    const float* qn_b = (const float*)d_in[44];
    const float* qp_W = (const float*)d_in[45];    const float* kp_W = (const float*)d_in[46];

    char* wsp = (char*)d_ws;
    size_t off = 0;
    auto alloc = [&](size_t bytes) { void* p = wsp + off; off = (off + bytes + 255) & ~(size_t)255; return p; };

    unsigned short* X    = (unsigned short*)alloc((size_t)MROWS * 360 * 2);
    unsigned short* XG   = (unsigned short*)alloc((size_t)MROWS * 520 * 2);
    unsigned short* FPC  = (unsigned short*)alloc((size_t)MROWS * 384 * 2);
    unsigned short* GIb  = (unsigned short*)alloc((size_t)MROWS * 1024 * 2);
    unsigned short* XQ   = (unsigned short*)alloc((size_t)MROWS * 264 * 2);
    unsigned short* T2b  = (unsigned short*)alloc((size_t)MROWS * 128 * 2);
    unsigned short* T3b  = (unsigned short*)alloc((size_t)MROWS * 128 * 2);
    unsigned short* QKSb = (unsigned short*)alloc((size_t)MROWS * 256 * 2);
    unsigned short* QWSb = (unsigned short*)alloc((size_t)MROWS * 40 * 2);
    unsigned short* OWNb = (unsigned short*)alloc((size_t)MROWS * 32 * 2);
    // composed bf16 weights
    unsigned short* FPW  = (unsigned short*)alloc(384 * 360 * 2);
    unsigned short* WRZ  = (unsigned short*)alloc(512 * 520 * 2);
    unsigned short* WIN  = (unsigned short*)alloc(256 * 264 * 2);
    unsigned short* WHN  = (unsigned short*)alloc(256 * 256 * 2);
    unsigned short* QWSW = (unsigned short*)alloc(40 * 264 * 2);
    unsigned short* WQKSO= (unsigned short*)alloc(256 * 32 * 2);
    unsigned short* rpW  = (unsigned short*)alloc(128 * 128 * 2);
    unsigned short* zbuf = (unsigned short*)alloc(256);
    // fp32 scratch
    float* WkAp = (float*)alloc(256 * 32 * 4);
    float* WvAp = (float*)alloc(256 * 32 * 4);
    float* WkEp = (float*)alloc(256 * 32 * 4);
    float* WvEp = (float*)alloc(256 * 32 * 4);
    float* Wkpp = (float*)alloc(256 * 32 * 4);
    float* WQKS_AE = (float*)alloc(256 * 256 * 4);
    float* WoVA = (float*)alloc(256 * 128 * 4);
    float* WoVE = (float*)alloc(256 * 128 * 4);
    float* bvAp = (float*)alloc(256 * 4);
    float* bvEp = (float*)alloc(256 * 4);
    float* bkpp = (float*)alloc(256 * 4);
    float* vall = (float*)alloc(768 * 4);
    float* qksb = (float*)alloc(256 * 4);
    float* fpb  = (float*)alloc(384 * 4);
    float* gbias= (float*)alloc(1024 * 4);
    float* rpb  = (float*)alloc(128 * 4);

    float* Qout = (float*)d_out;
    float* Hout = Qout + (size_t)MROWS * 22;

    auto mk = [](int type, const float* A, int sAi, int sAk, const float* B, int sBj, int sBk,
                 void* O, int sOi, int I, int J, int K, int nb = 1, int aB = 0, int bB = 0,
                 int oB = 0, const float* b1 = nullptr, const float* b2 = nullptr) {
        TOp o; o.type = type; o.A = A; o.sAi = sAi; o.sAk = sAk; o.B = B; o.sBj = sBj;
        o.sBk = sBk; o.O = O; o.sOi = sOi; o.I = I; o.J = J; o.K = K; o.nb = nb;
        o.aB = aB; o.bB = bB; o.oB = oB; o.bias1 = b1; o.bias2 = b2; return o;
    };
    auto tilesOf = [](const TOp& o) {
        return o.nb * (((o.I + 31) / 32) * ((o.J + 31) / 32));
    };

    {   // L1: raw-input composes + input cvts + zbuf
        TOpSet S; S.n = 0; int grid = 0;
        auto add = [&](TOp o) { S.tiles[S.n] = tilesOf(o); grid += S.tiles[S.n]; S.ops[S.n++] = o; };
        add(mk(2, hidden, 256, 1, nullptr, 0, 0, XG + 264, 520, MROWS, 256, 0));
        add(mk(2, own_feats, 32, 1, nullptr, 0, 0, OWNb, 32, MROWS, 32, 0));
        add(mk(3, nullptr, 0, 0, nullptr, 0, 0, zbuf, 32, 4, 32, 0));
        add(mk(1, aA_Wk, 256, 1, ally_W, 1, 32, WkAp, 32, 256, 32, 256));
        add(mk(1, aA_Wv, 256, 1, ally_W, 1, 32, WvAp, 32, 256, 32, 256));
        add(mk(1, aE_Wk, 256, 1, en_W, 1, 32, WkEp, 32, 256, 32, 256));
        add(mk(1, aE_Wv, 256, 1, en_W, 1, 32, WvEp, 32, 256, 32, 256));
        add(mk(1, kp_W, 256, 1, en_W, 1, 32, Wkpp, 32, 256, 32, 256));
        add(mk(1, aA_Wv, 256, 1, ally_b, 0, 1, bvAp, 1, 256, 1, 256));
        add(mk(1, aE_Wv, 256, 1, en_b, 0, 1, bvEp, 1, 256, 1, 256));
        add(mk(1, kp_W, 256, 1, en_b, 0, 1, bkpp, 1, 256, 1, 256));
        add(mk(4, own_b, 1, 1, nullptr, 0, 0, vall, 1, 256, 1, 0));
        add(mk(1, role_W1, 128, 1, pool_b2, 0, 1, rpb, 1, 128, 1, 128, 1, 0, 0, 0, role_b1));
        add(mk(1, gru_Wih, 264, 1, fuse_b2, 0, 1, gbias, 1, 512, 1, 256, 1, 0, 0, 0, gru_bih, gru_bhh));
        add(mk(1, gru_Wih + 512 * 264, 264, 1, fuse_b2, 0, 1, gbias + 512, 1, 256, 1, 256, 1, 0, 0, 0, gru_bih + 512));
        add(mk(4, gru_bhh + 512, 1, 1, nullptr, 0, 0, gbias + 768, 1, 256, 1, 0));
        compose_tiled<<<grid, 256, 0, stream>>>(S);
    }
    {   // L2: per-head QK compose, Wo@Wv, ctx bias halves
        TOpSet S; S.n = 0; int grid = 0;
        auto add = [&](TOp o) { S.tiles[S.n] = tilesOf(o); grid += S.tiles[S.n]; S.ops[S.n++] = o; };
        add(mk(1, WkAp, 1, 32, aA_Wq, 1, 256, WQKS_AE, 256, 32, 256, 64, 4, 2048, 16384, 8192));
        add(mk(1, WkEp, 1, 32, aE_Wq, 1, 256, WQKS_AE + 128 * 256, 256, 32, 256, 64, 4, 2048, 16384, 8192));
        add(mk(1, aA_Wo, 256, 1, WvAp, 1, 32, WoVA, 128, 256, 32, 64, 4, 64, 2048, 32));
        add(mk(1, aE_Wo, 256, 1, WvEp, 1, 32, WoVE, 128, 256, 32, 64, 4, 64, 2048, 32));
        add(mk(1, aA_Wo, 256, 1, bvAp, 0, 1, vall + 256, 1, 256, 1, 256));
        add(mk(1, aE_Wo, 256, 1, bvEp, 0, 1, vall + 512, 1, 256, 1, 256));
        compose_tiled<<<grid, 256, 0, stream>>>(S);
    }
    {   // L3: final composed weights + biases
        TOpSet S; S.n = 0; int grid = 0;
        auto add = [&](TOp o) { S.tiles[S.n] = tilesOf(o); grid += S.tiles[S.n]; S.ops[S.n++] = o; };
        add(mk(1, WQKS_AE, 256, 1, own_b, 0, 1, qksb, 1, 256, 1, 256));
        add(mk(1, fuse_W1, 768, 1, vall, 0, 1, fpb, 1, 256, 1, 768, 1, 0, 0, 0, fuse_b1));
        add(mk(1, pool_W1, 768, 1, own_b, 0, 1, fpb + 256, 1, 128, 1, 256, 1, 0, 0, 0, pool_b1));
        add(mk(0, WQKS_AE, 256, 1, own_W, 1, 32, WQKSO, 32, 256, 32, 256));
        // FPW fuse rows
        add(mk(0, fuse_W1, 768, 1, own_W, 1, 32, FPW, 360, 256, 32, 256));
        add(mk(3, nullptr, 0, 0, nullptr, 0, 0, FPW + 32, 360, 256, 72, 0));
        add(mk(0, fuse_W1 + 256, 768, 1, WoVA, 1, 128, FPW + 104, 360, 256, 128, 256));
        add(mk(0, fuse_W1 + 512, 768, 1, WoVE, 1, 128, FPW + 232, 360, 256, 128, 256));
        // FPW pool rows
        add(mk(0, pool_W1, 768, 1, own_W, 1, 32, FPW + 256 * 360, 360, 128, 32, 256));
        add(mk(0, pool_W1 + 256, 768, 1, ally_W, 1, 32, FPW + 256 * 360 + 32, 360, 128, 32, 256));
        add(mk(0, pool_W1 + 512, 768, 1, en_W, 1, 32, FPW + 256 * 360 + 64, 360, 128, 32, 256));
        add(mk(0, pool_W1 + 256, 768, 1, ally_b, 0, 1, FPW + 256 * 360 + 96, 360, 128, 1, 256));
        add(mk(0, pool_W1 + 512, 768, 1, en_b, 0, 1, FPW + 256 * 360 + 97, 360, 128, 1, 256));
        add(mk(3, nullptr, 0, 0, nullptr, 0, 0, FPW + 256 * 360 + 98, 360, 128, 262, 0));
        // WRZ / WIN / WHN
        add(mk(0, gru_Wih, 264, 1, fuse_W2, 1, 256, WRZ, 520, 512, 256, 256));
        add(mk(2, gru_Wih + 256, 264, 1, nullptr, 0, 0, WRZ + 256, 520, 512, 8, 0));
        add(mk(2, gru_Whh, 256, 1, nullptr, 0, 0, WRZ + 264, 520, 512, 256, 0));
        add(mk(0, gru_Wih + 512 * 264, 264, 1, fuse_W2, 1, 256, WIN, 264, 256, 256, 256));
        add(mk(2, gru_Wih + 512 * 264 + 256, 264, 1, nullptr, 0, 0, WIN + 256, 264, 256, 8, 0));
        add(mk(2, gru_Whh + 512 * 256, 256, 1, nullptr, 0, 0, WHN, 256, 256, 256, 0));
        // QWSW
        add(mk(0, Wkpp, 1, 32, qp_W, 1, 264, QWSW, 264, 32, 264, 256));
        add(mk(0, bkpp, 0, 1, qp_W, 1, 264, QWSW + 32 * 264, 264, 1, 264, 256));
        add(mk(2, qn_W, 256, 1, nullptr, 0, 0, QWSW + 33 * 264, 264, 6, 256, 0));
        add(mk(3, nullptr, 0, 0, nullptr, 0, 0, QWSW + 33 * 264 + 256, 264, 6, 8, 0));
        add(mk(3, nullptr, 0, 0, nullptr, 0, 0, QWSW + 39 * 264, 264, 1, 264, 0));
        // rpW
        add(mk(0, role_W1, 128, 1, pool_W2, 1, 128, rpW, 128, 128, 128, 128));
        compose_tiled<<<grid, 256, 0, stream>>>(S);
    }

    auto gemm = [&](const unsigned short* A, int lda, const unsigned short* Wm, const float* bias,
                    unsigned short* C, int ldc, int N, int K, int act) {
        gemm_bf16<<<dim3((N + 127) / 128, MROWS / 128), 256, 0, stream>>>(A, lda, Wm, bias, C, ldc, N, K, act, zbuf);
    };

    // ---- main chain ----
    gemm(OWNb, 32, WQKSO, qksb, QKSb, 256, 256, 32, 0);                  // QKS
    glue_attn<<<MROWS / 4, 256, 0, stream>>>(ally_feats, enemy_feats, own_feats, QKSb, X);
    gemm(X, 360, FPW, fpb, FPC, 384, 384, 360, 1);                       // fuse1+pool1 (+gelu)
    ln_fp<<<MROWS, 384, 0, stream>>>(FPC, fuse_g1, fuse_be1, pool_g1, pool_be1, XG, T2b);
    gemm(T2b, 128, rpW, rpb, T3b, 128, 128, 128, 1);                     // role1 (pool_W2 folded)
    ln_role<<<MROWS / 32, 256, 0, stream>>>(T3b, role_g1, role_be1, role_W2, role_b2, rln_g, rln_b, XG);
    gemm_gru<<<dim3(8, MROWS / 128), 256, 0, stream>>>(XG, WRZ, WIN, WHN, gbias, GIb, zbuf);
    glue_gru<<<MROWS, 256, 0, stream>>>(GIb, hidden, Hout, XQ, XG);
    gemm(XQ, 264, QWSW, nullptr, QWSb, 40, 40, 264, 0);                  // qws + c0 + q_normal
    glue_final<<<MROWS / 8, 256, 0, stream>>>(QWSb, enemy_feats, qn_b, Qout);
}